// Round 1
// baseline (354.369 us; speedup 1.0000x reference)
//
#include <hip/hip_runtime.h>
#include <stdint.h>

typedef __attribute__((ext_vector_type(8))) short bf16x8;
typedef __attribute__((ext_vector_type(4))) float f32x4;

__device__ __forceinline__ unsigned short f32_to_bf16(float f) {
  union { float f; unsigned int u; } v; v.f = f;
  unsigned int u = v.u;
  u += 0x7fffu + ((u >> 16) & 1u);   // round-to-nearest-even
  return (unsigned short)(u >> 16);
}

__device__ __forceinline__ void gload_lds16(const unsigned short* g, unsigned short* lds) {
  __builtin_amdgcn_global_load_lds(
      (const __attribute__((address_space(1))) unsigned int*)g,
      (__attribute__((address_space(3))) unsigned int*)lds,
      16, 0, 0);
}

// C[M,N] = scale * A[M,K] x B[N,K]^T  (A,B bf16 raw ushort, K-contiguous rows)
// MODE 0: C bf16 row-major. MODE 2: C fp32 row-major, scaled.
// Batched via blockIdx.z with element strides sA_/sB_/sC_.
template<int MODE>
__global__ __launch_bounds__(256, 2)
void gemm_bt(const unsigned short* __restrict__ A,
             const unsigned short* __restrict__ Bm,
             void* __restrict__ Cv,
             int M, int N, int K,
             long sA_, long sB_, long sC_,
             float scale)
{
  __shared__ unsigned short sA[128 * 32];
  __shared__ unsigned short sB[128 * 32];

  const int bz = blockIdx.z;
  const unsigned short* Ab = A + (long)bz * sA_;
  const unsigned short* Bb = Bm + (long)bz * sB_;

  const int m0 = blockIdx.x * 128;
  const int n0 = blockIdx.y * 128;

  const int t = threadIdx.x;       // 0..255
  const int lane = t & 63;
  const int w = t >> 6;            // wave 0..3 -> 2x2 grid of 64x64 subtiles
  const int wr = (w >> 1) * 64;
  const int wc = (w & 1) * 64;

  f32x4 acc[4][4];
#pragma unroll
  for (int i = 0; i < 4; ++i)
#pragma unroll
    for (int j = 0; j < 4; ++j)
      acc[i][j] = (f32x4){0.f, 0.f, 0.f, 0.f};

  // staging: 512 chunks of 16B per tile; thread t handles chunks t and t+256.
  // chunk c -> row c>>2 (32 bf16/row), k-offset (c&3)*8. LDS = row-major, no pad.
  const int r0 = t >> 2;
  const int kc = (t & 3) * 8;
  const unsigned short* Ap0 = Ab + (long)(m0 + r0) * K + kc;
  const unsigned short* Ap1 = Ab + (long)(m0 + r0 + 64) * K + kc;
  const unsigned short* Bp0 = Bb + (long)(n0 + r0) * K + kc;
  const unsigned short* Bp1 = Bb + (long)(n0 + r0 + 64) * K + kc;

  const int lrow = lane & 15;
  const int q8 = (lane >> 4) * 8;

  for (int k0 = 0; k0 < K; k0 += 32) {
    __syncthreads();
    gload_lds16(Ap0 + k0, &sA[t * 8]);
    gload_lds16(Ap1 + k0, &sA[t * 8 + 2048]);
    gload_lds16(Bp0 + k0, &sB[t * 8]);
    gload_lds16(Bp1 + k0, &sB[t * 8 + 2048]);
    __syncthreads();

    bf16x8 af[4], bfr[4];
#pragma unroll
    for (int i = 0; i < 4; ++i) {
      af[i]  = *(const bf16x8*)&sA[(wr + i * 16 + lrow) * 32 + q8];
      bfr[i] = *(const bf16x8*)&sB[(wc + i * 16 + lrow) * 32 + q8];
    }
#pragma unroll
    for (int mi = 0; mi < 4; ++mi)
#pragma unroll
      for (int ni = 0; ni < 4; ++ni)
        acc[mi][ni] = __builtin_amdgcn_mfma_f32_16x16x32_bf16(af[mi], bfr[ni], acc[mi][ni], 0, 0, 0);
  }

  // epilogue: C/D layout col = lane&15, row = (lane>>4)*4 + reg
  const int cl = lane & 15;
  const int rq = (lane >> 4) * 4;

  if (MODE == 2) {
    float* Cb = (float*)Cv + (long)bz * sC_;
#pragma unroll
    for (int mi = 0; mi < 4; ++mi) {
      const int rowb = m0 + wr + mi * 16 + rq;
#pragma unroll
      for (int ni = 0; ni < 4; ++ni) {
        const int col = n0 + wc + ni * 16 + cl;
#pragma unroll
        for (int r = 0; r < 4; ++r)
          Cb[(long)(rowb + r) * N + col] = acc[mi][ni][r] * scale;
      }
    }
  } else {
    unsigned short* Cb = (unsigned short*)Cv + (long)bz * sC_;
#pragma unroll
    for (int mi = 0; mi < 4; ++mi) {
      const int rowb = m0 + wr + mi * 16 + rq;
#pragma unroll
      for (int ni = 0; ni < 4; ++ni) {
        const int col = n0 + wc + ni * 16 + cl;
#pragma unroll
        for (int r = 0; r < 4; ++r)
          Cb[(long)(rowb + r) * N + col] = f32_to_bf16(acc[mi][ni][r]);
      }
    }
  }
}

// softmax over rows of 2048 fp32 -> bf16
__global__ __launch_bounds__(256)
void softmax_rows(const float* __restrict__ dist, unsigned short* __restrict__ attn) {
  const long row = blockIdx.x;
  const float4* in = (const float4*)(dist + row * 2048);
  const int t = threadIdx.x;
  float4 v0 = in[t];
  float4 v1 = in[t + 256];

  float m = fmaxf(fmaxf(fmaxf(v0.x, v0.y), fmaxf(v0.z, v0.w)),
                  fmaxf(fmaxf(v1.x, v1.y), fmaxf(v1.z, v1.w)));
#pragma unroll
  for (int off = 32; off > 0; off >>= 1)
    m = fmaxf(m, __shfl_xor(m, off, 64));

  __shared__ float redm[4];
  __shared__ float reds[4];
  if ((t & 63) == 0) redm[t >> 6] = m;
  __syncthreads();
  m = fmaxf(fmaxf(redm[0], redm[1]), fmaxf(redm[2], redm[3]));

  float e[8];
  e[0] = __expf(v0.x - m); e[1] = __expf(v0.y - m);
  e[2] = __expf(v0.z - m); e[3] = __expf(v0.w - m);
  e[4] = __expf(v1.x - m); e[5] = __expf(v1.y - m);
  e[6] = __expf(v1.z - m); e[7] = __expf(v1.w - m);

  float s = ((e[0] + e[1]) + (e[2] + e[3])) + ((e[4] + e[5]) + (e[6] + e[7]));
#pragma unroll
  for (int off = 32; off > 0; off >>= 1)
    s += __shfl_xor(s, off, 64);
  if ((t & 63) == 0) reds[t >> 6] = s;
  __syncthreads();
  s = (reds[0] + reds[1]) + (reds[2] + reds[3]);

  const float inv = 1.0f / s;
  ushort4 o0, o1;
  o0.x = f32_to_bf16(e[0] * inv); o0.y = f32_to_bf16(e[1] * inv);
  o0.z = f32_to_bf16(e[2] * inv); o0.w = f32_to_bf16(e[3] * inv);
  o1.x = f32_to_bf16(e[4] * inv); o1.y = f32_to_bf16(e[5] * inv);
  o1.z = f32_to_bf16(e[6] * inv); o1.w = f32_to_bf16(e[7] * inv);
  *(ushort4*)(attn + row * 2048 + t * 4) = o0;
  *(ushort4*)(attn + row * 2048 + 1024 + t * 4) = o1;
}

__global__ __launch_bounds__(256)
void cast_f32_bf16(const float* __restrict__ in, unsigned short* __restrict__ out, int n) {
  const int i = (blockIdx.x * 256 + threadIdx.x) * 4;
  if (i < n) {
    float4 v = *(const float4*)(in + i);
    ushort4 o;
    o.x = f32_to_bf16(v.x); o.y = f32_to_bf16(v.y);
    o.z = f32_to_bf16(v.z); o.w = f32_to_bf16(v.w);
    *(ushort4*)(out + i) = o;
  }
}

extern "C" void kernel_launch(void* const* d_in, const int* in_sizes, int n_in,
                              void* d_out, int out_size, void* d_ws, size_t ws_size,
                              hipStream_t stream) {
  const float* x  = (const float*)d_in[0];
  const float* Wq = (const float*)d_in[1];
  const float* Wk = (const float*)d_in[2];
  const float* Wv = (const float*)d_in[3];
  const float* Wo = (const float*)d_in[4];

  const long Bn = 4, S = 2048, D = 1024;
  const long MS = Bn * S;               // 8192

  float* out_p  = (float*)d_out;        // [B,S,D] = 8192x1024 fp32
  float* weight = out_p + MS * D;       // [B,S,S] = 4x2048x2048 fp32

  // workspace layout (elements of ushort/bf16); total 75.5 MB
  unsigned short* Wqb = (unsigned short*)d_ws;
  unsigned short* Wkb = Wqb + D * D;
  unsigned short* Wvb = Wkb + D * D;
  unsigned short* Wob = Wvb + D * D;
  unsigned short* xb  = Wob + D * D;    // [8192,1024]
  unsigned short* qb  = xb + MS * D;    // [8192,1024]
  unsigned short* kb  = qb + MS * D;    // [8192,1024]
  unsigned short* vtb = kb + MS * D;    // [4][1024][2048]  (v transposed per batch)
  unsigned short* attn = qb;            // alias over qb+kb: [4][2048][2048] bf16
  unsigned short* ctx  = xb;            // alias over xb (dead after v GEMM): [8192,1024]

  // casts to bf16
  cast_f32_bf16<<<1024, 256, 0, stream>>>(Wq, Wqb, (int)(D * D));
  cast_f32_bf16<<<1024, 256, 0, stream>>>(Wk, Wkb, (int)(D * D));
  cast_f32_bf16<<<1024, 256, 0, stream>>>(Wv, Wvb, (int)(D * D));
  cast_f32_bf16<<<1024, 256, 0, stream>>>(Wo, Wob, (int)(D * D));
  cast_f32_bf16<<<8192, 256, 0, stream>>>(x, xb, (int)(MS * D));

  // q = x Wq^T ; k = x Wk^T   (8192x1024x1024)
  gemm_bt<0><<<dim3(64, 8, 1), 256, 0, stream>>>(xb, Wqb, qb, 8192, 1024, 1024, 0, 0, 0, 1.f);
  gemm_bt<0><<<dim3(64, 8, 1), 256, 0, stream>>>(xb, Wkb, kb, 8192, 1024, 1024, 0, 0, 0, 1.f);
  // vT[b] = Wv x[b]^T : M=1024(j), N=2048(t), K=1024 -> vtb [b][1024][2048]
  gemm_bt<0><<<dim3(8, 16, 4), 256, 0, stream>>>(Wvb, xb, vtb, 1024, 2048, 1024,
                                                 0, S * D, D * S, 1.f);
  // dist[b] = scale * q[b] k[b]^T -> fp32 straight into d_out weight region
  gemm_bt<2><<<dim3(16, 16, 4), 256, 0, stream>>>(qb, kb, weight, 2048, 2048, 1024,
                                                  S * D, S * D, S * S, 0.04419417382415922f);
  // attn = softmax(dist) -> bf16
  softmax_rows<<<(int)(Bn * S), 256, 0, stream>>>(weight, attn);
  // ctx[b] = attn[b] vT[b]^T : M=2048, N=1024, K=2048
  gemm_bt<0><<<dim3(16, 8, 4), 256, 0, stream>>>(attn, vtb, ctx, 2048, 1024, 2048,
                                                 S * S, D * S, S * D, 1.f);
  // out = ctx Wo^T -> fp32 d_out
  gemm_bt<2><<<dim3(64, 8, 1), 256, 0, stream>>>(ctx, Wob, out_p, 8192, 1024, 1024,
                                                 0, 0, 0, 1.f);
}

// Round 2
// 313.780 us; speedup vs baseline: 1.1294x; 1.1294x over previous
//
#include <hip/hip_runtime.h>
#include <stdint.h>

typedef __attribute__((ext_vector_type(8))) short bf16x8;
typedef __attribute__((ext_vector_type(4))) float f32x4;

__device__ __forceinline__ unsigned short f32_to_bf16(float f) {
  union { float f; unsigned int u; } v; v.f = f;
  unsigned int u = v.u;
  u += 0x7fffu + ((u >> 16) & 1u);   // round-to-nearest-even
  return (unsigned short)(u >> 16);
}

__device__ __forceinline__ void gload_lds16(const unsigned short* g, unsigned short* lds) {
  __builtin_amdgcn_global_load_lds(
      (const __attribute__((address_space(1))) unsigned int*)g,
      (__attribute__((address_space(3))) unsigned int*)lds,
      16, 0, 0);
}

// C[M,N] = scale * A[M,K] x B[N,K]^T  (A,B bf16 raw ushort, K-contiguous rows,
// row strides lda/ldb/ldc in elements). Batched via blockIdx.z (strides sA_/sB_/sC_).
// MODE 0: C bf16. MODE 2: C fp32, scaled.
// K-loop: BK=64 as two stacked 128x32 panels (m97-proven bank layout, half the barriers).
template<int MODE>
__global__ __launch_bounds__(256, 2)
void gemm_bt(const unsigned short* __restrict__ A,
             const unsigned short* __restrict__ Bm,
             void* __restrict__ Cv,
             int M, int N, int K, int lda, int ldb, int ldc,
             long sA_, long sB_, long sC_,
             float scale)
{
  __shared__ unsigned short sA[2 * 128 * 32];   // 2 panels of 128x32
  __shared__ unsigned short sB[2 * 128 * 32];

  const int bz = blockIdx.z;
  const unsigned short* Ab = A + (long)bz * sA_;
  const unsigned short* Bb = Bm + (long)bz * sB_;

  const int m0 = blockIdx.x * 128;
  const int n0 = blockIdx.y * 128;

  const int t = threadIdx.x;       // 0..255
  const int lane = t & 63;
  const int w = t >> 6;            // wave 0..3 -> 2x2 grid of 64x64 subtiles
  const int wr = (w >> 1) * 64;
  const int wc = (w & 1) * 64;

  f32x4 acc[4][4];
#pragma unroll
  for (int i = 0; i < 4; ++i)
#pragma unroll
    for (int j = 0; j < 4; ++j)
      acc[i][j] = (f32x4){0.f, 0.f, 0.f, 0.f};

  // staging (per panel): 512 chunks of 16B; thread t handles chunks t and t+256.
  // chunk c -> row c>>2, k-offset (c&3)*8 within panel. Panel p adds +32 elements
  // of k (=64B imm offset) in global, +4096 ushort in LDS.
  const int r0 = t >> 2;
  const int kc = (t & 3) * 8;
  const unsigned short* Ap0 = Ab + (long)(m0 + r0) * lda + kc;
  const unsigned short* Ap1 = Ab + (long)(m0 + r0 + 64) * lda + kc;
  const unsigned short* Bp0 = Bb + (long)(n0 + r0) * ldb + kc;
  const unsigned short* Bp1 = Bb + (long)(n0 + r0 + 64) * ldb + kc;

  const int lrow = lane & 15;
  const int q8 = (lane >> 4) * 8;

  for (int k0 = 0; k0 < K; k0 += 64) {
    __syncthreads();
    gload_lds16(Ap0 + k0,      &sA[t * 8]);
    gload_lds16(Ap1 + k0,      &sA[t * 8 + 2048]);
    gload_lds16(Ap0 + k0 + 32, &sA[4096 + t * 8]);
    gload_lds16(Ap1 + k0 + 32, &sA[4096 + t * 8 + 2048]);
    gload_lds16(Bp0 + k0,      &sB[t * 8]);
    gload_lds16(Bp1 + k0,      &sB[t * 8 + 2048]);
    gload_lds16(Bp0 + k0 + 32, &sB[4096 + t * 8]);
    gload_lds16(Bp1 + k0 + 32, &sB[4096 + t * 8 + 2048]);
    __syncthreads();

#pragma unroll
    for (int s = 0; s < 2; ++s) {
      bf16x8 af[4], bfr[4];
#pragma unroll
      for (int i = 0; i < 4; ++i) {
        af[i]  = *(const bf16x8*)&sA[s * 4096 + (wr + i * 16 + lrow) * 32 + q8];
        bfr[i] = *(const bf16x8*)&sB[s * 4096 + (wc + i * 16 + lrow) * 32 + q8];
      }
#pragma unroll
      for (int mi = 0; mi < 4; ++mi)
#pragma unroll
        for (int ni = 0; ni < 4; ++ni)
          acc[mi][ni] = __builtin_amdgcn_mfma_f32_16x16x32_bf16(af[mi], bfr[ni], acc[mi][ni], 0, 0, 0);
    }
  }

  // epilogue: C/D layout col = lane&15, row = (lane>>4)*4 + reg
  const int cl = lane & 15;
  const int rq = (lane >> 4) * 4;

  if (MODE == 2) {
    float* Cb = (float*)Cv + (long)bz * sC_;
#pragma unroll
    for (int mi = 0; mi < 4; ++mi) {
      const int rowb = m0 + wr + mi * 16 + rq;
#pragma unroll
      for (int ni = 0; ni < 4; ++ni) {
        const int col = n0 + wc + ni * 16 + cl;
#pragma unroll
        for (int r = 0; r < 4; ++r)
          Cb[(long)(rowb + r) * ldc + col] = acc[mi][ni][r] * scale;
      }
    }
  } else {
    unsigned short* Cb = (unsigned short*)Cv + (long)bz * sC_;
#pragma unroll
    for (int mi = 0; mi < 4; ++mi) {
      const int rowb = m0 + wr + mi * 16 + rq;
#pragma unroll
      for (int ni = 0; ni < 4; ++ni) {
        const int col = n0 + wc + ni * 16 + cl;
#pragma unroll
        for (int r = 0; r < 4; ++r)
          Cb[(long)(rowb + r) * ldc + col] = f32_to_bf16(acc[mi][ni][r]);
      }
    }
  }
}

// softmax over rows of 2048 fp32 -> bf16
__global__ __launch_bounds__(256)
void softmax_rows(const float* __restrict__ dist, unsigned short* __restrict__ attn) {
  const long row = blockIdx.x;
  const float4* in = (const float4*)(dist + row * 2048);
  const int t = threadIdx.x;
  float4 v0 = in[t];
  float4 v1 = in[t + 256];

  float m = fmaxf(fmaxf(fmaxf(v0.x, v0.y), fmaxf(v0.z, v0.w)),
                  fmaxf(fmaxf(v1.x, v1.y), fmaxf(v1.z, v1.w)));
#pragma unroll
  for (int off = 32; off > 0; off >>= 1)
    m = fmaxf(m, __shfl_xor(m, off, 64));

  __shared__ float redm[4];
  __shared__ float reds[4];
  if ((t & 63) == 0) redm[t >> 6] = m;
  __syncthreads();
  m = fmaxf(fmaxf(redm[0], redm[1]), fmaxf(redm[2], redm[3]));

  float e[8];
  e[0] = __expf(v0.x - m); e[1] = __expf(v0.y - m);
  e[2] = __expf(v0.z - m); e[3] = __expf(v0.w - m);
  e[4] = __expf(v1.x - m); e[5] = __expf(v1.y - m);
  e[6] = __expf(v1.z - m); e[7] = __expf(v1.w - m);

  float s = ((e[0] + e[1]) + (e[2] + e[3])) + ((e[4] + e[5]) + (e[6] + e[7]));
#pragma unroll
  for (int off = 32; off > 0; off >>= 1)
    s += __shfl_xor(s, off, 64);
  if ((t & 63) == 0) reds[t >> 6] = s;
  __syncthreads();
  s = (reds[0] + reds[1]) + (reds[2] + reds[3]);

  const float inv = 1.0f / s;
  ushort4 o0, o1;
  o0.x = f32_to_bf16(e[0] * inv); o0.y = f32_to_bf16(e[1] * inv);
  o0.z = f32_to_bf16(e[2] * inv); o0.w = f32_to_bf16(e[3] * inv);
  o1.x = f32_to_bf16(e[4] * inv); o1.y = f32_to_bf16(e[5] * inv);
  o1.z = f32_to_bf16(e[6] * inv); o1.w = f32_to_bf16(e[7] * inv);
  *(ushort4*)(attn + row * 2048 + t * 4) = o0;
  *(ushort4*)(attn + row * 2048 + 1024 + t * 4) = o1;
}

// Fused cast of Wq,Wk,Wv,Wo (1M elems each) + x (8M elems) into one contiguous
// bf16 destination region. Segment boundaries are block-aligned (1024 blocks per
// weight), so the branch is wave-uniform.
__global__ __launch_bounds__(256)
void cast_all(const float* __restrict__ Wq, const float* __restrict__ Wk,
              const float* __restrict__ Wv, const float* __restrict__ Wo,
              const float* __restrict__ x, unsigned short* __restrict__ dst) {
  const long i = ((long)blockIdx.x * 256 + threadIdx.x) * 4;
  const float* src;
  long off;
  if (i < 4194304) {
    const int which = (int)(i >> 20);
    src = (which == 0) ? Wq : (which == 1) ? Wk : (which == 2) ? Wv : Wo;
    off = i & 1048575;
  } else {
    src = x;
    off = i - 4194304;
  }
  float4 v = *(const float4*)(src + off);
  ushort4 o;
  o.x = f32_to_bf16(v.x); o.y = f32_to_bf16(v.y);
  o.z = f32_to_bf16(v.z); o.w = f32_to_bf16(v.w);
  *(ushort4*)(dst + i) = o;
}

extern "C" void kernel_launch(void* const* d_in, const int* in_sizes, int n_in,
                              void* d_out, int out_size, void* d_ws, size_t ws_size,
                              hipStream_t stream) {
  const float* x  = (const float*)d_in[0];
  const float* Wq = (const float*)d_in[1];
  const float* Wk = (const float*)d_in[2];
  const float* Wv = (const float*)d_in[3];
  const float* Wo = (const float*)d_in[4];

  const long Bn = 4, S = 2048, D = 1024;
  const long MS = Bn * S;               // 8192

  float* out_p  = (float*)d_out;        // [B,S,D] = 8192x1024 fp32
  float* weight = out_p + MS * D;       // [B,S,S] = 4x2048x2048 fp32

  // workspace layout (ushort elements), 72 MB total:
  unsigned short* Wqb = (unsigned short*)d_ws;   // [2048,1024]: Wq rows then Wk rows
  unsigned short* Wvb = Wqb + 2 * D * D;
  unsigned short* Wob = Wvb + D * D;
  unsigned short* xb  = Wob + D * D;    // [8192,1024]
  unsigned short* qk  = xb + MS * D;    // [8192,2048]: cols 0..1023 = q, 1024.. = k
  unsigned short* vtb = qk + MS * 2048; // [4][1024][2048]  (v transposed per batch)
  unsigned short* attn = qk;            // alias (qk dead after dist): [4][2048][2048]
  unsigned short* ctx  = xb;            // alias (xb dead after v GEMM): [8192,1024]

  // one fused cast: weights + x -> contiguous bf16 region at Wqb
  cast_all<<<12288, 256, 0, stream>>>(Wq, Wk, Wv, Wo, x, Wqb);

  // qk = x [Wq;Wk]^T  (8192 x 2048 x 1024)
  gemm_bt<0><<<dim3(64, 16, 1), 256, 0, stream>>>(xb, Wqb, qk, 8192, 2048, 1024,
                                                  1024, 1024, 2048, 0, 0, 0, 1.f);
  // vT[b] = Wv x[b]^T : M=1024, N=2048, K=1024 -> vtb [b][1024][2048]
  gemm_bt<0><<<dim3(8, 16, 4), 256, 0, stream>>>(Wvb, xb, vtb, 1024, 2048, 1024,
                                                 1024, 1024, 2048, 0, S * D, D * S, 1.f);
  // dist[b] = scale * q[b] k[b]^T -> fp32 straight into d_out weight region
  gemm_bt<2><<<dim3(16, 16, 4), 256, 0, stream>>>(qk, qk + 1024, weight, 2048, 2048, 1024,
                                                  2048, 2048, 2048,
                                                  S * 2048, S * 2048, S * S,
                                                  0.04419417382415922f);
  // attn = softmax(dist) -> bf16 (aliases qk)
  softmax_rows<<<(int)(Bn * S), 256, 0, stream>>>(weight, attn);
  // ctx[b] = attn[b] vT[b]^T : M=2048, N=1024, K=2048
  gemm_bt<0><<<dim3(16, 8, 4), 256, 0, stream>>>(attn, vtb, ctx, 2048, 1024, 2048,
                                                 2048, 2048, 1024,
                                                 S * S, D * S, S * D, 1.f);
  // out = ctx Wo^T -> fp32 d_out
  gemm_bt<2><<<dim3(64, 8, 1), 256, 0, stream>>>(ctx, Wob, out_p, 8192, 1024, 1024,
                                                 1024, 1024, 1024, 0, 0, 0, 1.f);
}